// Round 1
// baseline (211.280 us; speedup 1.0000x reference)
//
#include <hip/hip_runtime.h>

// RadarSparseProcessor: out[v,o] = (sum_p sum_c F[v,p,c]*W[o,c]) / max(n[v],1)
// V=1048576, P=4, C_IN=4, C_OUT=32. Memory-bound: 196 MB traffic -> ~31us floor.
//
// Thread mapping: t -> (v = t>>3, oc = t&7). Each thread produces outputs
// [4*oc, 4*oc+4) of voxel v as a single coalesced float4 store (consecutive
// lanes -> consecutive 16B chunks). Feature loads are 8-lane-broadcast float4s
// (same cache lines reused within the wave, so HBM traffic stays 64B/voxel).

__global__ __launch_bounds__(256) void radar_pointnet_kernel(
    const float* __restrict__ feat,   // [V,4,4] fp32
    const float* __restrict__ Wm,     // [32,4]  fp32
    const int*   __restrict__ npts,   // [V]     int32
    float*       __restrict__ out,    // [V,32]  fp32
    int V)
{
    int t = blockIdx.x * blockDim.x + threadIdx.x;
    int v  = t >> 3;
    if (v >= V) return;
    int oc = t & 7;

    // Load the voxel's 4 points (4 channels each) and sum over points.
    const float4* f4 = (const float4*)feat;
    size_t fb = (size_t)v * 4;
    float4 p0 = f4[fb + 0];
    float4 p1 = f4[fb + 1];
    float4 p2 = f4[fb + 2];
    float4 p3 = f4[fb + 3];
    float sx = p0.x + p1.x + p2.x + p3.x;
    float sy = p0.y + p1.y + p2.y + p3.y;
    float sz = p0.z + p1.z + p2.z + p3.z;
    float sw = p0.w + p1.w + p2.w + p3.w;

    // W rows 4*oc .. 4*oc+3 (each row is one float4). L1-resident after warmup.
    const float4* Wf4 = (const float4*)Wm;
    int wb = oc * 4;
    float4 w0 = Wf4[wb + 0];
    float4 w1 = Wf4[wb + 1];
    float4 w2 = Wf4[wb + 2];
    float4 w3 = Wf4[wb + 3];

    int n = npts[v];
    float inv = 1.0f / (float)(n > 1 ? n : 1);

    float4 o;
    o.x = (sx * w0.x + sy * w0.y + sz * w0.z + sw * w0.w) * inv;
    o.y = (sx * w1.x + sy * w1.y + sz * w1.z + sw * w1.w) * inv;
    o.z = (sx * w2.x + sy * w2.y + sz * w2.z + sw * w2.w) * inv;
    o.w = (sx * w3.x + sy * w3.y + sz * w3.z + sw * w3.w) * inv;

    ((float4*)out)[(size_t)v * 8 + oc] = o;
}

extern "C" void kernel_launch(void* const* d_in, const int* in_sizes, int n_in,
                              void* d_out, int out_size, void* d_ws, size_t ws_size,
                              hipStream_t stream) {
    const float* feat = (const float*)d_in[0];   // [V,4,4]
    const float* Wm   = (const float*)d_in[1];   // [32,4]
    const int*   np   = (const int*)d_in[2];     // [V]
    float*       out  = (float*)d_out;           // [V,32]

    int V = in_sizes[0] / 16;                    // P*C_IN = 16 floats per voxel
    int threads = V * 8;                         // 8 threads per voxel
    int block = 256;
    int grid = (threads + block - 1) / block;

    radar_pointnet_kernel<<<grid, block, 0, stream>>>(feat, Wm, np, out, V);
}

// Round 2
// 197.275 us; speedup vs baseline: 1.0710x; 1.0710x over previous
//
#include <hip/hip_runtime.h>

// RadarSparseProcessor: out[v,o] = (sum_p sum_c F[v,p,c]*W[o,c]) / max(n[v],1)
// V=1048576, P=4, C_IN=4, C_OUT=32.
//
// R1 redesign (latency/issue-bound fix, R0 was 78us @ 2.2 TB/s, 27% peak):
//  - 4 lanes per voxel; lane q loads point q -> ONE fully-coalesced
//    global_load_dwordx4 per wave covers 16 voxels (zero duplication).
//  - point-sum via 2-round __shfl_xor butterfly (xor 1, xor 2) within the
//    4-lane group; all 4 lanes end with the channel sums.
//  - W rows (8 per lane = 32 floats) hoisted into registers ONCE per thread,
//    amortized over a grid-stride loop (~8 voxels/thread, 2048 blocks).
//  - lane q stores out cols [8q,8q+8) as two float4s; the 4 lanes of a group
//    jointly cover the voxel's 128B output line.
// VMEM wave-insts: 1.25/voxel (R0) -> 0.25/voxel.

__global__ __launch_bounds__(256) void radar_pointnet_kernel(
    const float* __restrict__ feat,   // [V,4,4] fp32
    const float* __restrict__ Wm,     // [32,4]  fp32
    const int*   __restrict__ npts,   // [V]     int32
    float*       __restrict__ out,    // [V,32]  fp32
    int V)
{
    const int tid = blockIdx.x * blockDim.x + threadIdx.x;
    const int q   = tid & 3;                      // lane-within-voxel
    const int g0  = tid >> 2;                     // first voxel for this thread
    const int ngroups = (gridDim.x * blockDim.x) >> 2;

    // Preload this lane's 8 W rows (rows 8q .. 8q+7). L1-resident, loop-invariant.
    const float4* __restrict__ Wf4 = (const float4*)Wm;
    float4 w[8];
#pragma unroll
    for (int j = 0; j < 8; ++j) w[j] = Wf4[q * 8 + j];

    const float4* __restrict__ f4 = (const float4*)feat;

#pragma unroll 2
    for (int v = g0; v < V; v += ngroups) {
        // lane q loads point q of voxel v: wave-contiguous 1KB load
        float4 p = f4[(size_t)v * 4 + q];

        // butterfly sum over the 4 points (lanes q^1, q^2 stay in-group)
        p.x += __shfl_xor(p.x, 1); p.y += __shfl_xor(p.y, 1);
        p.z += __shfl_xor(p.z, 1); p.w += __shfl_xor(p.w, 1);
        p.x += __shfl_xor(p.x, 2); p.y += __shfl_xor(p.y, 2);
        p.z += __shfl_xor(p.z, 2); p.w += __shfl_xor(p.w, 2);

        int n = npts[v];
        float inv = 1.0f / (float)(n > 1 ? n : 1);

        float4 o0, o1;
        o0.x = (p.x*w[0].x + p.y*w[0].y + p.z*w[0].z + p.w*w[0].w) * inv;
        o0.y = (p.x*w[1].x + p.y*w[1].y + p.z*w[1].z + p.w*w[1].w) * inv;
        o0.z = (p.x*w[2].x + p.y*w[2].y + p.z*w[2].z + p.w*w[2].w) * inv;
        o0.w = (p.x*w[3].x + p.y*w[3].y + p.z*w[3].z + p.w*w[3].w) * inv;
        o1.x = (p.x*w[4].x + p.y*w[4].y + p.z*w[4].z + p.w*w[4].w) * inv;
        o1.y = (p.x*w[5].x + p.y*w[5].y + p.z*w[5].z + p.w*w[5].w) * inv;
        o1.z = (p.x*w[6].x + p.y*w[6].y + p.z*w[6].z + p.w*w[6].w) * inv;
        o1.w = (p.x*w[7].x + p.y*w[7].y + p.z*w[7].z + p.w*w[7].w) * inv;

        float4* __restrict__ ob = (float4*)(out + (size_t)v * 32 + q * 8);
        ob[0] = o0;
        ob[1] = o1;
    }
}

extern "C" void kernel_launch(void* const* d_in, const int* in_sizes, int n_in,
                              void* d_out, int out_size, void* d_ws, size_t ws_size,
                              hipStream_t stream) {
    const float* feat = (const float*)d_in[0];   // [V,4,4]
    const float* Wm   = (const float*)d_in[1];   // [32,4]
    const int*   np   = (const int*)d_in[2];     // [V]
    float*       out  = (float*)d_out;           // [V,32]

    int V = in_sizes[0] / 16;                    // P*C_IN = 16 floats per voxel

    // 2048 blocks x 256 thr = 131072 voxel-groups -> ~8 voxels/thread at V=1M.
    int block = 256;
    int grid  = 2048;
    // For small V, don't launch more groups than voxels.
    int max_grid = (V * 4 + block - 1) / block;
    if (grid > max_grid) grid = max_grid;
    if (grid < 1) grid = 1;

    radar_pointnet_kernel<<<grid, block, 0, stream>>>(feat, Wm, np, out, V);
}

// Round 4
// 196.143 us; speedup vs baseline: 1.0772x; 1.0058x over previous
//
#include <hip/hip_runtime.h>

// RadarSparseProcessor: out[v,o] = (sum_p sum_c F[v,p,c]*W[o,c]) / max(n[v],1)
// V=1048576, P=4, C_IN=4, C_OUT=32.
//
// R3 = R2 with the compile fix: __builtin_nontemporal_* requires a clang
// native vector type, not HIP's float4 class -> use ext_vector_type(4).
//  - 4 lanes/voxel, lane q loads point q: one fully-coalesced 1KB wave-load.
//  - butterfly point-sum (__shfl_xor 1,2 stays in the 4-lane group).
//  - W register-resident per thread, amortized over grid-stride loop.
//  - sector-aligned stores: lane q writes rows [4q,4q+4) then [16+4q,16+4q+4),
//    so each store inst covers a full contiguous 64B half-line.
//  - non-temporal load/store on the touch-once streams; unroll 4 for MLP.

typedef float vf4 __attribute__((ext_vector_type(4)));

__global__ __launch_bounds__(256) void radar_pointnet_kernel(
    const float* __restrict__ feat,   // [V,4,4] fp32
    const float* __restrict__ Wm,     // [32,4]  fp32
    const int*   __restrict__ npts,   // [V]     int32
    float*       __restrict__ out,    // [V,32]  fp32
    int V)
{
    const int tid = blockIdx.x * blockDim.x + threadIdx.x;
    const int q   = tid & 3;                      // lane-within-voxel
    const int g0  = tid >> 2;                     // first voxel for this thread
    const int ngroups = (gridDim.x * blockDim.x) >> 2;

    // Lane q's 8 W rows: 4q..4q+3 (first output chunk) and 16+4q..16+4q+3
    // (second chunk). Loop-invariant, register-resident.
    const vf4* __restrict__ Wf4 = (const vf4*)Wm;
    vf4 w[8];
#pragma unroll
    for (int j = 0; j < 4; ++j) w[j]     = Wf4[q * 4 + j];
#pragma unroll
    for (int j = 0; j < 4; ++j) w[4 + j] = Wf4[16 + q * 4 + j];

    const vf4* __restrict__ f4 = (const vf4*)feat;
    vf4* __restrict__ ob = (vf4*)out;

#pragma unroll 4
    for (int v = g0; v < V; v += ngroups) {
        // lane q loads point q of voxel v: wave-contiguous 1KB, touch-once
        vf4 p = __builtin_nontemporal_load(&f4[(size_t)v * 4 + q]);

        // butterfly sum over the 4 points (lanes q^1, q^2 stay in-group)
        p.x += __shfl_xor(p.x, 1); p.y += __shfl_xor(p.y, 1);
        p.z += __shfl_xor(p.z, 1); p.w += __shfl_xor(p.w, 1);
        p.x += __shfl_xor(p.x, 2); p.y += __shfl_xor(p.y, 2);
        p.z += __shfl_xor(p.z, 2); p.w += __shfl_xor(p.w, 2);

        int n = npts[v];
        float inv = 1.0f / (float)(n > 1 ? n : 1);

        vf4 o0, o1;
        o0.x = (p.x*w[0].x + p.y*w[0].y + p.z*w[0].z + p.w*w[0].w) * inv;
        o0.y = (p.x*w[1].x + p.y*w[1].y + p.z*w[1].z + p.w*w[1].w) * inv;
        o0.z = (p.x*w[2].x + p.y*w[2].y + p.z*w[2].z + p.w*w[2].w) * inv;
        o0.w = (p.x*w[3].x + p.y*w[3].y + p.z*w[3].z + p.w*w[3].w) * inv;
        o1.x = (p.x*w[4].x + p.y*w[4].y + p.z*w[4].z + p.w*w[4].w) * inv;
        o1.y = (p.x*w[5].x + p.y*w[5].y + p.z*w[5].z + p.w*w[5].w) * inv;
        o1.z = (p.x*w[6].x + p.y*w[6].y + p.z*w[6].z + p.w*w[6].w) * inv;
        o1.w = (p.x*w[7].x + p.y*w[7].y + p.z*w[7].z + p.w*w[7].w) * inv;

        // inst0: bytes [0,64) of the voxel's 128B line, inst1: bytes [64,128)
        __builtin_nontemporal_store(o0, &ob[(size_t)v * 8 + q]);
        __builtin_nontemporal_store(o1, &ob[(size_t)v * 8 + 4 + q]);
    }
}

extern "C" void kernel_launch(void* const* d_in, const int* in_sizes, int n_in,
                              void* d_out, int out_size, void* d_ws, size_t ws_size,
                              hipStream_t stream) {
    const float* feat = (const float*)d_in[0];   // [V,4,4]
    const float* Wm   = (const float*)d_in[1];   // [32,4]
    const int*   np   = (const int*)d_in[2];     // [V]
    float*       out  = (float*)d_out;           // [V,32]

    int V = in_sizes[0] / 16;                    // P*C_IN = 16 floats per voxel

    int block = 256;
    int grid  = 2048;                            // ~8 voxels/thread at V=1M
    int max_grid = (V * 4 + block - 1) / block;
    if (grid > max_grid) grid = max_grid;
    if (grid < 1) grid = 1;

    radar_pointnet_kernel<<<grid, block, 0, stream>>>(feat, Wm, np, out, V);
}

// Round 5
// 189.021 us; speedup vs baseline: 1.1178x; 1.0377x over previous
//
#include <hip/hip_runtime.h>

// RadarSparseProcessor: out[v,o] = (sum_p sum_c F[v,p,c]*W[o,c]) / max(n[v],1)
// V=1048576, P=4, C_IN=4, C_OUT=32.
//
// R5: attack memory-level parallelism. The grid-stride loop's runtime trip
// count forced guarded unrolling (loads serialized behind each iteration's
// bounds check + stores -> ~1 load chain in flight/wave -> ~3.2 TB/s).
// At V=1M, grid 2048x256 gives EXACTLY 8 iterations/thread: specialize that
// path with a compile-time loop, batch all 8 feat + 8 npts loads up front
// (8KB outstanding per wave), then compute+store.
//  - stores back to CACHED (L2 write-allocate merges half-lines into full
//    128B lines; nt write-through was the suspected half-rate path).
//  - nt kept on feat loads only (touch-once, keep L2 for the write stream).
//  - 1/n via __builtin_amdgcn_rcpf (n in {1..4}; no -ffast-math, the full
//    fp32 divide is ~10 VALU insts).

typedef float vf4 __attribute__((ext_vector_type(4)));

__device__ __forceinline__ void load_w(const vf4* __restrict__ Wf4, int q, vf4* w) {
#pragma unroll
    for (int j = 0; j < 4; ++j) w[j]     = Wf4[q * 4 + j];
#pragma unroll
    for (int j = 0; j < 4; ++j) w[4 + j] = Wf4[16 + q * 4 + j];
}

__device__ __forceinline__ void voxel_body(vf4 p, int n, const vf4* w,
                                           vf4* __restrict__ ob, size_t v, int q) {
    // butterfly sum over the 4 points (lanes q^1, q^2 stay in-group)
    p.x += __shfl_xor(p.x, 1); p.y += __shfl_xor(p.y, 1);
    p.z += __shfl_xor(p.z, 1); p.w += __shfl_xor(p.w, 1);
    p.x += __shfl_xor(p.x, 2); p.y += __shfl_xor(p.y, 2);
    p.z += __shfl_xor(p.z, 2); p.w += __shfl_xor(p.w, 2);

    float inv = __builtin_amdgcn_rcpf((float)(n > 1 ? n : 1));

    vf4 o0, o1;
    o0.x = (p.x*w[0].x + p.y*w[0].y + p.z*w[0].z + p.w*w[0].w) * inv;
    o0.y = (p.x*w[1].x + p.y*w[1].y + p.z*w[1].z + p.w*w[1].w) * inv;
    o0.z = (p.x*w[2].x + p.y*w[2].y + p.z*w[2].z + p.w*w[2].w) * inv;
    o0.w = (p.x*w[3].x + p.y*w[3].y + p.z*w[3].z + p.w*w[3].w) * inv;
    o1.x = (p.x*w[4].x + p.y*w[4].y + p.z*w[4].z + p.w*w[4].w) * inv;
    o1.y = (p.x*w[5].x + p.y*w[5].y + p.z*w[5].z + p.w*w[5].w) * inv;
    o1.z = (p.x*w[6].x + p.y*w[6].y + p.z*w[6].z + p.w*w[6].w) * inv;
    o1.w = (p.x*w[7].x + p.y*w[7].y + p.z*w[7].z + p.w*w[7].w) * inv;

    // lane q covers bytes [64q/4..), full 64B sectors per inst
    ob[v * 8 + q]     = o0;
    ob[v * 8 + 4 + q] = o1;
}

// Specialized: V == 1048576, grid == 2048x256 -> exactly 8 voxels/thread.
__global__ __launch_bounds__(256) void radar_pointnet_v8(
    const float* __restrict__ feat, const float* __restrict__ Wm,
    const int* __restrict__ npts, float* __restrict__ out)
{
    constexpr int NG = 131072;                    // voxel-groups in grid
    const int tid = blockIdx.x * 256 + threadIdx.x;
    const int q   = tid & 3;
    const int g0  = tid >> 2;

    vf4 w[8];
    load_w((const vf4*)Wm, q, w);

    const vf4* __restrict__ f4 = (const vf4*)feat;
    vf4* __restrict__ ob = (vf4*)out;

    vf4 p[8];
    int n[8];
#pragma unroll
    for (int k = 0; k < 8; ++k) {                 // all 16 loads issue up front
        size_t v = (size_t)g0 + (size_t)k * NG;
        p[k] = __builtin_nontemporal_load(&f4[v * 4 + q]);
        n[k] = npts[v];
    }
#pragma unroll
    for (int k = 0; k < 8; ++k) {
        size_t v = (size_t)g0 + (size_t)k * NG;
        voxel_body(p[k], n[k], w, ob, v, q);
    }
}

// Generic fallback (any V).
__global__ __launch_bounds__(256) void radar_pointnet_gen(
    const float* __restrict__ feat, const float* __restrict__ Wm,
    const int* __restrict__ npts, float* __restrict__ out, int V)
{
    const int tid = blockIdx.x * blockDim.x + threadIdx.x;
    const int q   = tid & 3;
    const int g0  = tid >> 2;
    const int ngroups = (gridDim.x * blockDim.x) >> 2;

    vf4 w[8];
    load_w((const vf4*)Wm, q, w);

    const vf4* __restrict__ f4 = (const vf4*)feat;
    vf4* __restrict__ ob = (vf4*)out;

    for (int v = g0; v < V; v += ngroups) {
        vf4 p = __builtin_nontemporal_load(&f4[(size_t)v * 4 + q]);
        voxel_body(p, npts[v], w, ob, (size_t)v, q);
    }
}

extern "C" void kernel_launch(void* const* d_in, const int* in_sizes, int n_in,
                              void* d_out, int out_size, void* d_ws, size_t ws_size,
                              hipStream_t stream) {
    const float* feat = (const float*)d_in[0];   // [V,4,4]
    const float* Wm   = (const float*)d_in[1];   // [32,4]
    const int*   np   = (const int*)d_in[2];     // [V]
    float*       out  = (float*)d_out;           // [V,32]

    int V = in_sizes[0] / 16;                    // P*C_IN = 16 floats per voxel

    if (V == 1048576) {
        radar_pointnet_v8<<<2048, 256, 0, stream>>>(feat, Wm, np, out);
    } else {
        int block = 256;
        int grid  = 2048;
        int max_grid = (V * 4 + block - 1) / block;
        if (grid > max_grid) grid = max_grid;
        if (grid < 1) grid = 1;
        radar_pointnet_gen<<<grid, block, 0, stream>>>(feat, Wm, np, out, V);
    }
}